// Round 1
// baseline (1523.551 us; speedup 1.0000x reference)
//
#include <hip/hip_runtime.h>
#include <math.h>

// Problem constants (fixed by the reference):
constexpr int Cc = 512;   // channels
constexpr int Hh = 8;     // heads
constexpr int Dd = 64;    // head dim
constexpr int Nn = 2048;  // kv length
constexpr int Bb = 8;     // batch

// ---------------------------------------------------------------------------
// SGEMM: Cm[M,Nc] = A[M,K] * Bm[Nc,K]^T (+ bias)   — all f32, row-major.
// 64x64 tile, K-steps of 16, 4x4 per-thread microtile. Assumes M%64==0,
// Nc%64==0, K%16==0 (true for all three uses here).
// ---------------------------------------------------------------------------
__global__ __launch_bounds__(256) void sgemm_nt_kernel(
    const float* __restrict__ A, const float* __restrict__ Bm,
    const float* __restrict__ bias, float* __restrict__ Cm,
    int M, int Nc, int K)
{
  __shared__ float As[16][68];   // [k][m], pad 68 -> 16B-aligned rows, no conflicts
  __shared__ float Bs[16][68];   // [k][n]
  const int tid = threadIdx.x;
  const int tx = tid & 15, ty = tid >> 4;
  const int n0 = blockIdx.x * 64, m0 = blockIdx.y * 64;
  const int lm = tid >> 2;          // 0..63 tile row
  const int lk = (tid & 3) << 2;    // 0,4,8,12 k sub-offset
  float acc[4][4] = {};
  const float* Ap = A + (size_t)(m0 + lm) * K + lk;
  const float* Bp = Bm + (size_t)(n0 + lm) * K + lk;

  for (int k0 = 0; k0 < K; k0 += 16) {
    const float4 a = *(const float4*)(Ap + k0);
    const float4 b = *(const float4*)(Bp + k0);
    __syncthreads();
    As[lk+0][lm] = a.x; As[lk+1][lm] = a.y; As[lk+2][lm] = a.z; As[lk+3][lm] = a.w;
    Bs[lk+0][lm] = b.x; Bs[lk+1][lm] = b.y; Bs[lk+2][lm] = b.z; Bs[lk+3][lm] = b.w;
    __syncthreads();
#pragma unroll
    for (int kk = 0; kk < 16; ++kk) {
      float av[4], bv[4];
#pragma unroll
      for (int i = 0; i < 4; ++i) av[i] = As[kk][ty*4 + i];
#pragma unroll
      for (int j = 0; j < 4; ++j) bv[j] = Bs[kk][tx*4 + j];
#pragma unroll
      for (int i = 0; i < 4; ++i)
#pragma unroll
        for (int j = 0; j < 4; ++j)
          acc[i][j] = fmaf(av[i], bv[j], acc[i][j]);
    }
  }

  const int col = n0 + tx*4;
#pragma unroll
  for (int i = 0; i < 4; ++i) {
    float4 o;
    o.x = acc[i][0]; o.y = acc[i][1]; o.z = acc[i][2]; o.w = acc[i][3];
    if (bias) {
      o.x += bias[col+0]; o.y += bias[col+1]; o.z += bias[col+2]; o.w += bias[col+3];
    }
    *(float4*)&Cm[(size_t)(m0 + ty*4 + i) * Nc + col] = o;
  }
}

// ---------------------------------------------------------------------------
// Flash attention (f32). One block = 32 query rows x 1 head x 1 batch.
// 256 threads: thread t -> row r=t/8, col-group c=t%8 (8 output cols each).
// Online softmax; K/V staged in LDS in 64-key tiles; P via LDS.
// ---------------------------------------------------------------------------
__global__ __launch_bounds__(256) void attn_fwd_kernel(
    const float* __restrict__ qh,    // (TQ, C) = (TQ, H*D)
    const float* __restrict__ kvb,   // (B*N, 2*C): [.. ,0,h,d]=K, [..,1,h,d]=V
    float* __restrict__ attno,       // (TQ, C)
    const int* __restrict__ qlen)    // (B)
{
  const int qt = blockIdx.x;
  const int h  = blockIdx.y;
  const int b  = blockIdx.z;

  int off = 0;
#pragma unroll
  for (int i = 0; i < Bb; ++i) { int Li = qlen[i]; off += (i < b) ? Li : 0; }
  const int Lb = qlen[b];
  if (qt * 32 >= Lb) return;               // uniform exit for excess tiles
  const int rows = min(32, Lb - qt * 32);

  __shared__ float Ks[64][68];
  __shared__ float Vs[64][68];
  __shared__ float Ps[32][68];

  const int tid = threadIdx.x;
  const int r = tid >> 3;   // 0..31 query row in tile
  const int c = tid & 7;    // 0..7 column group

  // Q row -> registers (8 lanes of a row read the same data; L1-served)
  float qr[64];
  {
    const bool valid = (r < rows);
    const float* qp = qh + (size_t)(off + qt*32 + (valid ? r : 0)) * Cc + h * Dd;
#pragma unroll
    for (int d = 0; d < 64; d += 4) {
      float4 qv = valid ? *(const float4*)(qp + d) : make_float4(0.f,0.f,0.f,0.f);
      qr[d+0]=qv.x; qr[d+1]=qv.y; qr[d+2]=qv.z; qr[d+3]=qv.w;
    }
  }

  float m = -INFINITY, l = 0.f;
  float acc[8] = {};
  const float scale = 0.125f;  // D^-0.5
  const size_t kvbase = (size_t)b * Nn * (2*Cc) + (size_t)h * Dd;

  for (int nt = 0; nt < Nn/64; ++nt) {
    __syncthreads();   // previous tile's P*V reads done
    // stage K,V tile (64 keys x 64 dims each)
    for (int i = tid; i < 64*16; i += 256) {
      const int nr = i >> 4, d4 = (i & 15) << 2;
      const size_t g = kvbase + (size_t)(nt*64 + nr) * (2*Cc) + d4;
      *(float4*)&Ks[nr][d4] = *(const float4*)&kvb[g];
      *(float4*)&Vs[nr][d4] = *(const float4*)&kvb[g + Cc];
    }
    __syncthreads();

    // scores: this thread handles keys n = c + jj*8
    float s[8];
#pragma unroll
    for (int jj = 0; jj < 8; ++jj) {
      const int n = c + jj*8;
      float acs = 0.f;
#pragma unroll
      for (int d = 0; d < 64; d += 4) {
        const float4 k4 = *(const float4*)&Ks[n][d];
        acs = fmaf(qr[d+0], k4.x, acs);
        acs = fmaf(qr[d+1], k4.y, acs);
        acs = fmaf(qr[d+2], k4.z, acs);
        acs = fmaf(qr[d+3], k4.w, acs);
      }
      s[jj] = acs * scale;
    }

    // row max across the 8 lanes of this row
    float tmax = s[0];
#pragma unroll
    for (int jj = 1; jj < 8; ++jj) tmax = fmaxf(tmax, s[jj]);
    tmax = fmaxf(tmax, __shfl_xor(tmax, 1));
    tmax = fmaxf(tmax, __shfl_xor(tmax, 2));
    tmax = fmaxf(tmax, __shfl_xor(tmax, 4));
    const float mnew = fmaxf(m, tmax);
    const float alpha = __expf(m - mnew);   // exp(-inf)=0 on first tile

    float psum = 0.f;
#pragma unroll
    for (int jj = 0; jj < 8; ++jj) {
      const float p = __expf(s[jj] - mnew);
      Ps[r][c + jj*8] = p;
      psum += p;
    }
    psum += __shfl_xor(psum, 1);
    psum += __shfl_xor(psum, 2);
    psum += __shfl_xor(psum, 4);
    l = l * alpha + psum;
    m = mnew;
#pragma unroll
    for (int i = 0; i < 8; ++i) acc[i] *= alpha;
    __syncthreads();   // Ps visible to all lanes of each row

    // acc += P(row) * V ; this thread owns cols c*8 .. c*8+7
#pragma unroll
    for (int n4 = 0; n4 < 16; ++n4) {
      const float4 p4 = *(const float4*)&Ps[r][n4*4];
      const float pv[4] = {p4.x, p4.y, p4.z, p4.w};
#pragma unroll
      for (int u = 0; u < 4; ++u) {
        const int n = n4*4 + u;
        const float4 v0 = *(const float4*)&Vs[n][c*8];
        const float4 v1 = *(const float4*)&Vs[n][c*8 + 4];
        acc[0] = fmaf(pv[u], v0.x, acc[0]);
        acc[1] = fmaf(pv[u], v0.y, acc[1]);
        acc[2] = fmaf(pv[u], v0.z, acc[2]);
        acc[3] = fmaf(pv[u], v0.w, acc[3]);
        acc[4] = fmaf(pv[u], v1.x, acc[4]);
        acc[5] = fmaf(pv[u], v1.y, acc[5]);
        acc[6] = fmaf(pv[u], v1.z, acc[6]);
        acc[7] = fmaf(pv[u], v1.w, acc[7]);
      }
    }
  }

  if (r < rows) {
    const float inv = 1.f / l;
    float* dst = attno + (size_t)(off + qt*32 + r) * Cc + h*Dd + c*8;
    float4 o0, o1;
    o0.x = acc[0]*inv; o0.y = acc[1]*inv; o0.z = acc[2]*inv; o0.w = acc[3]*inv;
    o1.x = acc[4]*inv; o1.y = acc[5]*inv; o1.z = acc[6]*inv; o1.w = acc[7]*inv;
    *(float4*)(dst)     = o0;
    *(float4*)(dst + 4) = o1;
  }
}

// ---------------------------------------------------------------------------
extern "C" void kernel_launch(void* const* d_in, const int* in_sizes, int n_in,
                              void* d_out, int out_size, void* d_ws, size_t ws_size,
                              hipStream_t stream)
{
  const float* x     = (const float*)d_in[0];  // (B,N,C)
  const float* q     = (const float*)d_in[1];  // (TQ,C)
  const float* Wq    = (const float*)d_in[2];  // (C,C)
  const float* Wkv   = (const float*)d_in[3];  // (2C,C)
  const float* Wproj = (const float*)d_in[4];  // (C,C)
  const float* bproj = (const float*)d_in[5];  // (C)
  const int*   qlen  = (const int*)d_in[6];    // (B)

  const int TQ = in_sizes[1] / Cc;   // 11776 (multiple of 64)
  const int BN = in_sizes[0] / Cc;   // 16384

  float* qh    = (float*)d_ws;                 // TQ*C
  float* kvb   = qh  + (size_t)TQ * Cc;        // BN*2C
  float* attno = kvb + (size_t)BN * (2*Cc);    // TQ*C

  // 1) qh = q @ Wq^T
  sgemm_nt_kernel<<<dim3(Cc/64, TQ/64), 256, 0, stream>>>(q, Wq, nullptr, qh, TQ, Cc, Cc);
  // 2) kv = x @ Wkv^T   (k/v interleaved per token: cols [0,512)=K, [512,1024)=V)
  sgemm_nt_kernel<<<dim3((2*Cc)/64, BN/64), 256, 0, stream>>>(x, Wkv, nullptr, kvb, BN, 2*Cc, Cc);
  // 3) attention
  attn_fwd_kernel<<<dim3((TQ + 31)/32, Hh, Bb), 256, 0, stream>>>(qh, kvb, attno, qlen);
  // 4) out = attno @ Wproj^T + bproj
  sgemm_nt_kernel<<<dim3(Cc/64, TQ/64), 256, 0, stream>>>(attno, Wproj, bproj, (float*)d_out, TQ, Cc, Cc);
}

// Round 2
// 647.296 us; speedup vs baseline: 2.3537x; 2.3537x over previous
//
#include <hip/hip_runtime.h>
#include <hip/hip_bf16.h>
#include <math.h>

// Problem constants (fixed by the reference):
constexpr int Cc = 512;   // channels
constexpr int Hh = 8;     // heads
constexpr int Dd = 64;    // head dim
constexpr int Nn = 2048;  // kv length
constexpr int Bb = 8;     // batch

typedef __attribute__((ext_vector_type(8))) short short8;
typedef __attribute__((ext_vector_type(4))) float f32x4;

static __device__ __forceinline__ ushort f2bf(float v) {
  __hip_bfloat16 h = __float2bfloat16(v);
  return *reinterpret_cast<ushort*>(&h);
}

// ---------------------------------------------------------------------------
// SGEMM: C[M,Nc] = A[M,K] * Bm[Nc,K]^T (+ bias)  — f32 compute, row-major.
// MODE 0: f32 out (+bias). MODE 1: bf16 out. MODE 2: bf16 hi + lo (split).
// 64x64 tile, K-steps of 16, 4x4 microtile. M%64==0, Nc%64==0, K%16==0.
// ---------------------------------------------------------------------------
template <int MODE>
__global__ __launch_bounds__(256) void sgemm_nt_kernel(
    const float* __restrict__ A, const float* __restrict__ Bm,
    const float* __restrict__ bias, float* __restrict__ Cf,
    ushort* __restrict__ Chi, ushort* __restrict__ Clo,
    int M, int Nc, int K)
{
  __shared__ float As[16][68];
  __shared__ float Bs[16][68];
  const int tid = threadIdx.x;
  const int tx = tid & 15, ty = tid >> 4;
  const int n0 = blockIdx.x * 64, m0 = blockIdx.y * 64;
  const int lm = tid >> 2;
  const int lk = (tid & 3) << 2;
  float acc[4][4] = {};
  const float* Ap = A + (size_t)(m0 + lm) * K + lk;
  const float* Bp = Bm + (size_t)(n0 + lm) * K + lk;

  for (int k0 = 0; k0 < K; k0 += 16) {
    const float4 a = *(const float4*)(Ap + k0);
    const float4 b = *(const float4*)(Bp + k0);
    __syncthreads();
    As[lk+0][lm] = a.x; As[lk+1][lm] = a.y; As[lk+2][lm] = a.z; As[lk+3][lm] = a.w;
    Bs[lk+0][lm] = b.x; Bs[lk+1][lm] = b.y; Bs[lk+2][lm] = b.z; Bs[lk+3][lm] = b.w;
    __syncthreads();
#pragma unroll
    for (int kk = 0; kk < 16; ++kk) {
      float av[4], bv[4];
#pragma unroll
      for (int i = 0; i < 4; ++i) av[i] = As[kk][ty*4 + i];
#pragma unroll
      for (int j = 0; j < 4; ++j) bv[j] = Bs[kk][tx*4 + j];
#pragma unroll
      for (int i = 0; i < 4; ++i)
#pragma unroll
        for (int j = 0; j < 4; ++j)
          acc[i][j] = fmaf(av[i], bv[j], acc[i][j]);
    }
  }

  const int col = n0 + tx*4;
#pragma unroll
  for (int i = 0; i < 4; ++i) {
    const size_t orow = (size_t)(m0 + ty*4 + i) * Nc + col;
    if (MODE == 0) {
      float4 o;
      o.x = acc[i][0]; o.y = acc[i][1]; o.z = acc[i][2]; o.w = acc[i][3];
      if (bias) {
        o.x += bias[col+0]; o.y += bias[col+1]; o.z += bias[col+2]; o.w += bias[col+3];
      }
      *(float4*)&Cf[orow] = o;
    } else if (MODE == 1) {
      ushort4 u;
      u.x = f2bf(acc[i][0]); u.y = f2bf(acc[i][1]);
      u.z = f2bf(acc[i][2]); u.w = f2bf(acc[i][3]);
      *(ushort4*)&Chi[orow] = u;
    } else {
      ushort4 uh, ul;
#pragma unroll
      for (int j = 0; j < 4; ++j) {
        const ushort hb = f2bf(acc[i][j]);
        __hip_bfloat16 hh = *reinterpret_cast<const __hip_bfloat16*>(&hb);
        const float rem = acc[i][j] - __bfloat162float(hh);
        ((ushort*)&uh)[j] = hb;
        ((ushort*)&ul)[j] = f2bf(rem);
      }
      *(ushort4*)&Chi[orow] = uh;
      *(ushort4*)&Clo[orow] = ul;
    }
  }
}

// ---------------------------------------------------------------------------
// MFMA flash attention. Block = 64 q-rows x 1 head x 1 batch, 4 waves.
// Wave w owns q-rows [w*16, w*16+16). KV tiles of 64 keys staged in LDS.
// mfma_f32_16x16x32_bf16; C/D: col=lane&15, row=(lane>>4)*4+reg (verified).
// A/B frags: [m/n = lane&15][k = (lane>>4)*8 + j] — identical k-mapping on
// both operands, so pairing is consistent regardless of internal permutation.
// LDS rows padded to 72 bf16 (144B) to break the 128B bank alias.
// ---------------------------------------------------------------------------
__global__ __launch_bounds__(256) void attn_mfma_kernel(
    const ushort* __restrict__ qhi,  // (TQ, C) bf16
    const ushort* __restrict__ qlo,  // (TQ, C) bf16
    const ushort* __restrict__ kbf,  // (B*N, C) bf16
    const ushort* __restrict__ vtb,  // (C, B*N) bf16  (V^T)
    float* __restrict__ attno,       // (TQ, C) f32
    const int* __restrict__ qlen)    // (B)
{
  const int qt = blockIdx.x, h = blockIdx.y, b = blockIdx.z;
  int off = 0, Lb = 0;
#pragma unroll
  for (int i = 0; i < Bb; ++i) {
    const int Li = qlen[i];
    off += (i < b) ? Li : 0;
    Lb = (i == b) ? Li : Lb;
  }
  if (qt * 64 >= Lb) return;   // uniform over block; lengths are %64==0

  constexpr int KP = 72;       // padded LDS row stride (bf16 elems)
  __shared__ ushort Ks[64 * KP];
  __shared__ ushort Vs[64 * KP];
  __shared__ ushort Ps[4 * 16 * KP];

  const int tid = threadIdx.x;
  const int w = tid >> 6;
  const int lane = tid & 63;
  const int c = lane & 15;
  const int g = lane >> 4;

  // Q fragments (held across the whole KV loop): rows w*16 + (lane&15)
  short8 qh0, qh1, ql0, ql1;
  {
    const size_t base = (size_t)(off + qt*64 + w*16 + c) * Cc + h*Dd + g*8;
    qh0 = *(const short8*)(qhi + base);
    qh1 = *(const short8*)(qhi + base + 32);
    ql0 = *(const short8*)(qlo + base);
    ql1 = *(const short8*)(qlo + base + 32);
  }

  float m_r[4] = {-INFINITY, -INFINITY, -INFINITY, -INFINITY};
  float l_r[4] = {0.f, 0.f, 0.f, 0.f};
  f32x4 acc_o[4] = {};   // [cb]: output cols cb*16 + c

  const float scale = 0.125f;  // D^-0.5
  const size_t kbase = (size_t)b * Nn * Cc + h * Dd;
  const size_t vbase = (size_t)h * Dd * (Bb * Nn) + (size_t)b * Nn;
  ushort* Pw = Ps + w * 16 * KP;

  for (int nt = 0; nt < Nn/64; ++nt) {
    __syncthreads();   // previous tile's LDS reads complete
#pragma unroll
    for (int it = 0; it < 2; ++it) {
      const int i = tid + it * 256;
      const int row = i >> 3, c8 = (i & 7) * 8;
      *(short8*)&Ks[row*KP + c8] =
          *(const short8*)&kbf[kbase + (size_t)(nt*64 + row) * Cc + c8];
      *(short8*)&Vs[row*KP + c8] =
          *(const short8*)&vtb[vbase + (size_t)row * (Bb*Nn) + nt*64 + c8];
    }
    __syncthreads();

    // ---- S = Q K^T (split-Q: hi + lo) ----
    f32x4 acc_s[4] = {};
#pragma unroll
    for (int nb = 0; nb < 4; ++nb) {
      const short8 k0 = *(const short8*)&Ks[(nb*16 + c)*KP + g*8];
      const short8 k1 = *(const short8*)&Ks[(nb*16 + c)*KP + 32 + g*8];
      acc_s[nb] = __builtin_amdgcn_mfma_f32_16x16x32_bf16(qh0, k0, acc_s[nb], 0,0,0);
      acc_s[nb] = __builtin_amdgcn_mfma_f32_16x16x32_bf16(qh1, k1, acc_s[nb], 0,0,0);
      acc_s[nb] = __builtin_amdgcn_mfma_f32_16x16x32_bf16(ql0, k0, acc_s[nb], 0,0,0);
      acc_s[nb] = __builtin_amdgcn_mfma_f32_16x16x32_bf16(ql1, k1, acc_s[nb], 0,0,0);
    }

    // ---- online softmax: lane holds S[row g*4+r][col nb*16+c] ----
    float alpha[4];
#pragma unroll
    for (int r = 0; r < 4; ++r) {
      const float s0 = acc_s[0][r]*scale, s1 = acc_s[1][r]*scale;
      const float s2 = acc_s[2][r]*scale, s3 = acc_s[3][r]*scale;
      float mx = fmaxf(fmaxf(s0, s1), fmaxf(s2, s3));
      mx = fmaxf(mx, __shfl_xor(mx, 1));
      mx = fmaxf(mx, __shfl_xor(mx, 2));
      mx = fmaxf(mx, __shfl_xor(mx, 4));
      mx = fmaxf(mx, __shfl_xor(mx, 8));
      const float mn = fmaxf(m_r[r], mx);
      alpha[r] = __expf(m_r[r] - mn);   // first tile: exp(-inf)=0
      m_r[r] = mn;
      const float p0 = __expf(s0 - mn), p1 = __expf(s1 - mn);
      const float p2 = __expf(s2 - mn), p3 = __expf(s3 - mn);
      const int pr = (g*4 + r)*KP + c;
      Pw[pr +  0] = f2bf(p0);
      Pw[pr + 16] = f2bf(p1);
      Pw[pr + 32] = f2bf(p2);
      Pw[pr + 48] = f2bf(p3);
      float ps = p0 + p1 + p2 + p3;
      ps += __shfl_xor(ps, 1);
      ps += __shfl_xor(ps, 2);
      ps += __shfl_xor(ps, 4);
      ps += __shfl_xor(ps, 8);
      l_r[r] = l_r[r]*alpha[r] + ps;
    }
#pragma unroll
    for (int cb = 0; cb < 4; ++cb)
#pragma unroll
      for (int r = 0; r < 4; ++r)
        acc_o[cb][r] *= alpha[r];

    __syncthreads();   // P visible (wave-local, but keep it simple+safe)

    // ---- O += P V ----
    const short8 pf0 = *(const short8*)&Pw[c*KP + g*8];
    const short8 pf1 = *(const short8*)&Pw[c*KP + 32 + g*8];
#pragma unroll
    for (int cb = 0; cb < 4; ++cb) {
      const short8 v0 = *(const short8*)&Vs[(cb*16 + c)*KP + g*8];
      const short8 v1 = *(const short8*)&Vs[(cb*16 + c)*KP + 32 + g*8];
      acc_o[cb] = __builtin_amdgcn_mfma_f32_16x16x32_bf16(pf0, v0, acc_o[cb], 0,0,0);
      acc_o[cb] = __builtin_amdgcn_mfma_f32_16x16x32_bf16(pf1, v1, acc_o[cb], 0,0,0);
    }
  }

  // ---- epilogue: normalize + store f32 ----
#pragma unroll
  for (int r = 0; r < 4; ++r) {
    const float inv = 1.f / l_r[r];
    float* dst = attno + (size_t)(off + qt*64 + w*16 + g*4 + r) * Cc + h*Dd + c;
#pragma unroll
    for (int cb = 0; cb < 4; ++cb)
      dst[cb*16] = acc_o[cb][r] * inv;
  }
}

// ---------------------------------------------------------------------------
extern "C" void kernel_launch(void* const* d_in, const int* in_sizes, int n_in,
                              void* d_out, int out_size, void* d_ws, size_t ws_size,
                              hipStream_t stream)
{
  const float* x     = (const float*)d_in[0];  // (B,N,C)
  const float* q     = (const float*)d_in[1];  // (TQ,C)
  const float* Wq    = (const float*)d_in[2];  // (C,C)
  const float* Wkv   = (const float*)d_in[3];  // (2C,C): rows [0,C)=Wk, [C,2C)=Wv
  const float* Wproj = (const float*)d_in[4];  // (C,C)
  const float* bproj = (const float*)d_in[5];  // (C)
  const int*   qlen  = (const int*)d_in[6];    // (B)

  const int TQ = in_sizes[1] / Cc;   // 11776 (multiple of 64)
  const int BN = in_sizes[0] / Cc;   // 16384

  // workspace layout (bytes)
  char* p = (char*)d_ws;
  ushort* q_hi = (ushort*)p;                 p += (size_t)TQ * Cc * 2;
  ushort* q_lo = (ushort*)p;                 p += (size_t)TQ * Cc * 2;
  ushort* k_bf = (ushort*)p;                 p += (size_t)BN * Cc * 2;
  ushort* v_t  = (ushort*)p;                 p += (size_t)Cc * BN * 2;
  float*  attno = (float*)p;                 // TQ*Cc f32

  // 1) q_hi/q_lo = split-bf16(q @ Wq^T)
  sgemm_nt_kernel<2><<<dim3(Cc/64, TQ/64), 256, 0, stream>>>(
      q, Wq, nullptr, nullptr, q_hi, q_lo, TQ, Cc, Cc);
  // 2) k_bf = bf16(x @ Wk^T)            (BN, C)
  sgemm_nt_kernel<1><<<dim3(Cc/64, BN/64), 256, 0, stream>>>(
      x, Wkv, nullptr, nullptr, k_bf, nullptr, BN, Cc, Cc);
  // 3) v_t = bf16(Wv @ x^T) = V^T       (C, BN)
  sgemm_nt_kernel<1><<<dim3(BN/64, Cc/64), 256, 0, stream>>>(
      Wkv + (size_t)Cc * Cc, x, nullptr, nullptr, v_t, nullptr, Cc, BN, Cc);
  // 4) attention (MFMA)
  attn_mfma_kernel<<<dim3(TQ/64, Hh, Bb), 256, 0, stream>>>(
      q_hi, q_lo, k_bf, v_t, attno, qlen);
  // 5) out = attno @ Wproj^T + bproj
  sgemm_nt_kernel<0><<<dim3(Cc/64, TQ/64), 256, 0, stream>>>(
      attno, Wproj, bproj, (float*)d_out, nullptr, nullptr, TQ, Cc, Cc);
}

// Round 4
// 370.085 us; speedup vs baseline: 4.1168x; 1.7490x over previous
//
#include <hip/hip_runtime.h>
#include <hip/hip_bf16.h>
#include <math.h>

// Problem constants (fixed by the reference):
constexpr int Cc = 512;   // channels
constexpr int Hh = 8;     // heads
constexpr int Dd = 64;    // head dim
constexpr int Nn = 2048;  // kv length
constexpr int Bb = 8;     // batch
constexpr int GK = 512;   // K dim of every GEMM here

typedef __attribute__((ext_vector_type(8))) short short8;
typedef __attribute__((ext_vector_type(4))) float f32x4;

static __device__ __forceinline__ ushort f2bf(float v) {
  __hip_bfloat16 h = __float2bfloat16(v);
  return *reinterpret_cast<ushort*>(&h);
}
static __device__ __forceinline__ float bf2f(ushort u) {
  __hip_bfloat16 h = *reinterpret_cast<__hip_bfloat16*>(&u);
  return __bfloat162float(h);
}

static __device__ __forceinline__ void gl_lds16(const void* g, void* l) {
  __builtin_amdgcn_global_load_lds(
      (const __attribute__((address_space(1))) void*)g,
      (__attribute__((address_space(3))) void*)l, 16, 0, 0);
}

// ---------------------------------------------------------------------------
// split f32 -> bf16 hi + lo residual
// ---------------------------------------------------------------------------
__global__ __launch_bounds__(256) void split_bf16_kernel(
    const float* __restrict__ in, ushort* __restrict__ hi,
    ushort* __restrict__ lo, int n4)   // n4 = n/4
{
  const int i = blockIdx.x * 256 + threadIdx.x;
  if (i >= n4) return;
  const float4 v = *(const float4*)(in + (size_t)i * 4);
  ushort4 uh, ul;
  const float vv[4] = {v.x, v.y, v.z, v.w};
#pragma unroll
  for (int j = 0; j < 4; ++j) {
    const ushort hb = f2bf(vv[j]);
    ((ushort*)&uh)[j] = hb;
    ((ushort*)&ul)[j] = f2bf(vv[j] - bf2f(hb));
  }
  *(ushort4*)(hi + (size_t)i * 4) = uh;
  *(ushort4*)(lo + (size_t)i * 4) = ul;
}

// ---------------------------------------------------------------------------
// Split-bf16 MFMA GEMM: C[M,Nc] = (Ah+Al)[M,K] * ((Bh+Bl)[Nc,K])^T (+bias)
//   = Ah Bh + Ah Bl + Al Bh   (lo*lo dropped, ~2^-18 rel)
// 128x128 tile, BK=32, 256 threads = 4 waves in 2x2, each wave 64x64.
// K hardcoded 512. MODE 0: f32 + bias. MODE 1: bf16. MODE 2: bf16 hi+lo.
// Fragment mapping identical to the verified attention kernel.
// ---------------------------------------------------------------------------
template <int MODE>
__global__ __launch_bounds__(256) void mfma_nt_kernel(
    const ushort* __restrict__ Ah, const ushort* __restrict__ Al,
    const ushort* __restrict__ Bh, const ushort* __restrict__ Bl,
    const float* __restrict__ bias, float* __restrict__ Cf,
    ushort* __restrict__ Chi, ushort* __restrict__ Clo, int Nc)
{
  __shared__ ushort lAh[128 * 32];
  __shared__ ushort lAl[128 * 32];
  __shared__ ushort lBh[128 * 32];
  __shared__ ushort lBl[128 * 32];

  const int tid = threadIdx.x;
  const int w = tid >> 6, lane = tid & 63;
  const int c = lane & 15, g = lane >> 4;
  const int wr = (w >> 1) * 64, wc = (w & 1) * 64;
  const int m0 = blockIdx.y * 128, n0 = blockIdx.x * 128;

  const int sr = tid >> 2;          // staging row 0..63
  const int sk = (tid & 3) * 8;     // staging k-offset (ushorts)

  f32x4 acc[4][4] = {};

  for (int k0 = 0; k0 < GK; k0 += 32) {
    __syncthreads();   // previous compute done before overwrite
    {
      const size_t a1 = (size_t)(m0 + sr) * GK + k0 + sk;
      const size_t b1 = (size_t)(n0 + sr) * GK + k0 + sk;
      const size_t a2 = a1 + (size_t)64 * GK;
      const size_t b2 = b1 + (size_t)64 * GK;
      char* dA  = (char*)lAh + w * 1024;
      char* dAl = (char*)lAl + w * 1024;
      char* dB  = (char*)lBh + w * 1024;
      char* dBl = (char*)lBl + w * 1024;
      gl_lds16(Ah + a1, dA);
      gl_lds16(Al + a1, dAl);
      gl_lds16(Bh + b1, dB);
      gl_lds16(Bl + b1, dBl);
      gl_lds16(Ah + a2, dA + 4096);
      gl_lds16(Al + a2, dAl + 4096);
      gl_lds16(Bh + b2, dB + 4096);
      gl_lds16(Bl + b2, dBl + 4096);
    }
    __syncthreads();   // staging visible

    short8 ah[4], al[4], bh[4], bl[4];
#pragma unroll
    for (int i = 0; i < 4; ++i) {
      const int ar = (wr + i * 16 + c) * 32 + g * 8;
      const int br = (wc + i * 16 + c) * 32 + g * 8;
      ah[i] = *(const short8*)&lAh[ar];
      al[i] = *(const short8*)&lAl[ar];
      bh[i] = *(const short8*)&lBh[br];
      bl[i] = *(const short8*)&lBl[br];
    }
#pragma unroll
    for (int mi = 0; mi < 4; ++mi)
#pragma unroll
      for (int nj = 0; nj < 4; ++nj) {
        acc[mi][nj] = __builtin_amdgcn_mfma_f32_16x16x32_bf16(ah[mi], bl[nj], acc[mi][nj], 0,0,0);
        acc[mi][nj] = __builtin_amdgcn_mfma_f32_16x16x32_bf16(al[mi], bh[nj], acc[mi][nj], 0,0,0);
        acc[mi][nj] = __builtin_amdgcn_mfma_f32_16x16x32_bf16(ah[mi], bh[nj], acc[mi][nj], 0,0,0);
      }
  }

  // epilogue: D row = m0+wr+mi*16+g*4+r, col = n0+wc+nj*16+c
#pragma unroll
  for (int mi = 0; mi < 4; ++mi) {
#pragma unroll
    for (int r = 0; r < 4; ++r) {
      const size_t rb = (size_t)(m0 + wr + mi * 16 + g * 4 + r) * Nc;
#pragma unroll
      for (int nj = 0; nj < 4; ++nj) {
        const int col = n0 + wc + nj * 16 + c;
        const float v = acc[mi][nj][r];
        if (MODE == 0) {
          Cf[rb + col] = v + bias[col];
        } else if (MODE == 1) {
          Chi[rb + col] = f2bf(v);
        } else {
          const ushort hb = f2bf(v);
          Chi[rb + col] = hb;
          Clo[rb + col] = f2bf(v - bf2f(hb));
        }
      }
    }
  }
}

// ---------------------------------------------------------------------------
// MFMA flash attention (round-2 structure; epilogue writes hi/lo bf16).
// ---------------------------------------------------------------------------
__global__ __launch_bounds__(256) void attn_mfma_kernel(
    const ushort* __restrict__ qhi,  // (TQ, C) bf16
    const ushort* __restrict__ qlo,  // (TQ, C) bf16
    const ushort* __restrict__ kbf,  // (B*N, C) bf16
    const ushort* __restrict__ vtb,  // (C, B*N) bf16  (V^T)
    ushort* __restrict__ ohi,        // (TQ, C) bf16 hi
    ushort* __restrict__ olo,        // (TQ, C) bf16 lo
    const int* __restrict__ qlen)    // (B)
{
  const int qt = blockIdx.x, h = blockIdx.y, b = blockIdx.z;
  int off = 0, Lb = 0;
#pragma unroll
  for (int i = 0; i < Bb; ++i) {
    const int Li = qlen[i];
    off += (i < b) ? Li : 0;
    Lb = (i == b) ? Li : Lb;
  }
  if (qt * 64 >= Lb) return;   // uniform over block; lengths are %64==0

  constexpr int KP = 72;       // padded LDS row stride (bf16 elems)
  __shared__ ushort Ks[64 * KP];
  __shared__ ushort Vs[64 * KP];
  __shared__ ushort Ps[4 * 16 * KP];

  const int tid = threadIdx.x;
  const int w = tid >> 6;
  const int lane = tid & 63;
  const int c = lane & 15;
  const int g = lane >> 4;

  short8 qh0, qh1, ql0, ql1;
  {
    const size_t base = (size_t)(off + qt*64 + w*16 + c) * Cc + h*Dd + g*8;
    qh0 = *(const short8*)(qhi + base);
    qh1 = *(const short8*)(qhi + base + 32);
    ql0 = *(const short8*)(qlo + base);
    ql1 = *(const short8*)(qlo + base + 32);
  }

  float m_r[4] = {-INFINITY, -INFINITY, -INFINITY, -INFINITY};
  float l_r[4] = {0.f, 0.f, 0.f, 0.f};
  f32x4 acc_o[4] = {};

  const float scale = 0.125f;
  const size_t kbase = (size_t)b * Nn * Cc + h * Dd;
  const size_t vbase = (size_t)h * Dd * (Bb * Nn) + (size_t)b * Nn;
  ushort* Pw = Ps + w * 16 * KP;

  for (int nt = 0; nt < Nn/64; ++nt) {
    __syncthreads();
#pragma unroll
    for (int it = 0; it < 2; ++it) {
      const int i = tid + it * 256;
      const int row = i >> 3, c8 = (i & 7) * 8;
      *(short8*)&Ks[row*KP + c8] =
          *(const short8*)&kbf[kbase + (size_t)(nt*64 + row) * Cc + c8];
      *(short8*)&Vs[row*KP + c8] =
          *(const short8*)&vtb[vbase + (size_t)row * (Bb*Nn) + nt*64 + c8];
    }
    __syncthreads();

    f32x4 acc_s[4] = {};
#pragma unroll
    for (int nb = 0; nb < 4; ++nb) {
      const short8 k0 = *(const short8*)&Ks[(nb*16 + c)*KP + g*8];
      const short8 k1 = *(const short8*)&Ks[(nb*16 + c)*KP + 32 + g*8];
      acc_s[nb] = __builtin_amdgcn_mfma_f32_16x16x32_bf16(qh0, k0, acc_s[nb], 0,0,0);
      acc_s[nb] = __builtin_amdgcn_mfma_f32_16x16x32_bf16(qh1, k1, acc_s[nb], 0,0,0);
      acc_s[nb] = __builtin_amdgcn_mfma_f32_16x16x32_bf16(ql0, k0, acc_s[nb], 0,0,0);
      acc_s[nb] = __builtin_amdgcn_mfma_f32_16x16x32_bf16(ql1, k1, acc_s[nb], 0,0,0);
    }

    float alpha[4];
#pragma unroll
    for (int r = 0; r < 4; ++r) {
      const float s0 = acc_s[0][r]*scale, s1 = acc_s[1][r]*scale;
      const float s2 = acc_s[2][r]*scale, s3 = acc_s[3][r]*scale;
      float mx = fmaxf(fmaxf(s0, s1), fmaxf(s2, s3));
      mx = fmaxf(mx, __shfl_xor(mx, 1));
      mx = fmaxf(mx, __shfl_xor(mx, 2));
      mx = fmaxf(mx, __shfl_xor(mx, 4));
      mx = fmaxf(mx, __shfl_xor(mx, 8));
      const float mn = fmaxf(m_r[r], mx);
      alpha[r] = __expf(m_r[r] - mn);
      m_r[r] = mn;
      const float p0 = __expf(s0 - mn), p1 = __expf(s1 - mn);
      const float p2 = __expf(s2 - mn), p3 = __expf(s3 - mn);
      const int pr = (g*4 + r)*KP + c;
      Pw[pr +  0] = f2bf(p0);
      Pw[pr + 16] = f2bf(p1);
      Pw[pr + 32] = f2bf(p2);
      Pw[pr + 48] = f2bf(p3);
      float ps = p0 + p1 + p2 + p3;
      ps += __shfl_xor(ps, 1);
      ps += __shfl_xor(ps, 2);
      ps += __shfl_xor(ps, 4);
      ps += __shfl_xor(ps, 8);
      l_r[r] = l_r[r]*alpha[r] + ps;
    }
#pragma unroll
    for (int cb = 0; cb < 4; ++cb)
#pragma unroll
      for (int r = 0; r < 4; ++r)
        acc_o[cb][r] *= alpha[r];

    __syncthreads();

    const short8 pf0 = *(const short8*)&Pw[c*KP + g*8];
    const short8 pf1 = *(const short8*)&Pw[c*KP + 32 + g*8];
#pragma unroll
    for (int cb = 0; cb < 4; ++cb) {
      const short8 v0 = *(const short8*)&Vs[(cb*16 + c)*KP + g*8];
      const short8 v1 = *(const short8*)&Vs[(cb*16 + c)*KP + 32 + g*8];
      acc_o[cb] = __builtin_amdgcn_mfma_f32_16x16x32_bf16(pf0, v0, acc_o[cb], 0,0,0);
      acc_o[cb] = __builtin_amdgcn_mfma_f32_16x16x32_bf16(pf1, v1, acc_o[cb], 0,0,0);
    }
  }

#pragma unroll
  for (int r = 0; r < 4; ++r) {
    const float inv = 1.f / l_r[r];
    const size_t rb = (size_t)(off + qt*64 + w*16 + g*4 + r) * Cc + h*Dd + c;
#pragma unroll
    for (int cb = 0; cb < 4; ++cb) {
      const float o = acc_o[cb][r] * inv;
      const ushort hb = f2bf(o);
      ohi[rb + cb*16] = hb;
      olo[rb + cb*16] = f2bf(o - bf2f(hb));
    }
  }
}

// ---------------------------------------------------------------------------
extern "C" void kernel_launch(void* const* d_in, const int* in_sizes, int n_in,
                              void* d_out, int out_size, void* d_ws, size_t ws_size,
                              hipStream_t stream)
{
  const float* x     = (const float*)d_in[0];  // (B,N,C)
  const float* q     = (const float*)d_in[1];  // (TQ,C)
  const float* Wq    = (const float*)d_in[2];  // (C,C)
  const float* Wkv   = (const float*)d_in[3];  // (2C,C): rows [0,C)=Wk, [C,2C)=Wv
  const float* Wproj = (const float*)d_in[4];  // (C,C)
  const float* bproj = (const float*)d_in[5];  // (C)
  const int*   qlen  = (const int*)d_in[6];    // (B)

  const int TQ = in_sizes[1] / Cc;   // 11776 (multiple of 128)
  const int BN = in_sizes[0] / Cc;   // 16384

  const size_t szQ = (size_t)TQ * Cc * 2;        // 12,058,624 B
  const size_t szX = (size_t)BN * Cc * 2;        // 16,777,216 B
  const size_t szW = (size_t)(4 * Cc) * Cc * 2;  // [Wq|Wkv|Wproj] as ushorts

  // workspace carve; aliasing:
  //   R1 (2*szQ): q split hi/lo  -> later k_bf (szX <= 2*szQ)
  //   R2 (2*szX): x split hi/lo  -> later attno hi/lo (2*szQ <= 2*szX)
  char* p = (char*)d_ws;
  ushort* qs_hi = (ushort*)p;                       // R1
  ushort* qs_lo = (ushort*)(p + szQ);
  ushort* k_bf  = (ushort*)p;                       // alias (after qh GEMM)
  p += 2 * szQ;
  ushort* xs_hi = (ushort*)p;                       // R2
  ushort* xs_lo = (ushort*)(p + szX);
  ushort* at_hi = (ushort*)p;                       // alias (after v GEMM)
  ushort* at_lo = (ushort*)(p + szQ);
  p += 2 * szX;
  ushort* w_hi  = (ushort*)p;  p += szW;            // [Wq | Wkv | Wproj] hi
  ushort* w_lo  = (ushort*)p;  p += szW;
  ushort* q_hi  = (ushort*)p;  p += szQ;
  ushort* q_lo  = (ushort*)p;  p += szQ;
  ushort* v_t   = (ushort*)p;                       // szX

  ushort* wq_hi = w_hi;
  ushort* wq_lo = w_lo;
  ushort* wk_hi = w_hi + (size_t)Cc * Cc;
  ushort* wk_lo = w_lo + (size_t)Cc * Cc;
  ushort* wv_hi = wk_hi + (size_t)Cc * Cc;
  ushort* wv_lo = wk_lo + (size_t)Cc * Cc;
  ushort* wp_hi = wv_hi + (size_t)Cc * Cc;
  ushort* wp_lo = wv_lo + (size_t)Cc * Cc;

  // --- splits ---
  {
    const int nq = TQ * Cc / 4, nx = BN * Cc / 4;
    const int nwq = Cc * Cc / 4, nwkv = 2 * Cc * Cc / 4;
    split_bf16_kernel<<<(nq + 255)/256, 256, 0, stream>>>(q, qs_hi, qs_lo, nq);
    split_bf16_kernel<<<(nx + 255)/256, 256, 0, stream>>>(x, xs_hi, xs_lo, nx);
    split_bf16_kernel<<<(nwq + 255)/256, 256, 0, stream>>>(Wq, wq_hi, wq_lo, nwq);
    split_bf16_kernel<<<(nwkv + 255)/256, 256, 0, stream>>>(Wkv, wk_hi, wk_lo, nwkv);
    split_bf16_kernel<<<(nwq + 255)/256, 256, 0, stream>>>(Wproj, wp_hi, wp_lo, nwq);
  }

  // 1) q_hi/q_lo = split(q @ Wq^T)       M=TQ, N=C
  mfma_nt_kernel<2><<<dim3(Cc/128, TQ/128), 256, 0, stream>>>(
      qs_hi, qs_lo, wq_hi, wq_lo, nullptr, nullptr, q_hi, q_lo, Cc);
  // 2) k_bf = bf16(x @ Wk^T)             M=BN, N=C   (writes R1 — qs dead now)
  mfma_nt_kernel<1><<<dim3(Cc/128, BN/128), 256, 0, stream>>>(
      xs_hi, xs_lo, wk_hi, wk_lo, nullptr, nullptr, k_bf, nullptr, Cc);
  // 3) v_t = bf16(Wv @ x^T)              M=C, N=BN
  mfma_nt_kernel<1><<<dim3(BN/128, Cc/128), 256, 0, stream>>>(
      wv_hi, wv_lo, xs_hi, xs_lo, nullptr, nullptr, v_t, nullptr, BN);
  // 4) attention (writes attno hi/lo into R2 — xs dead now)
  attn_mfma_kernel<<<dim3(TQ/64, Hh, Bb), 256, 0, stream>>>(
      q_hi, q_lo, k_bf, v_t, at_hi, at_lo, qlen);
  // 5) out = attno @ Wproj^T + bproj     M=TQ, N=C
  mfma_nt_kernel<0><<<dim3(Cc/128, TQ/128), 256, 0, stream>>>(
      at_hi, at_lo, wp_hi, wp_lo, bproj, (float*)d_out, nullptr, nullptr, Cc);
}

// Round 5
// 295.044 us; speedup vs baseline: 5.1638x; 1.2543x over previous
//
#include <hip/hip_runtime.h>
#include <hip/hip_bf16.h>
#include <math.h>

// Problem constants (fixed by the reference):
constexpr int Cc = 512;   // channels
constexpr int Hh = 8;     // heads
constexpr int Dd = 64;    // head dim
constexpr int Nn = 2048;  // kv length
constexpr int Bb = 8;     // batch
constexpr int GK = 512;   // K dim of every GEMM here

typedef __attribute__((ext_vector_type(8))) short short8;
typedef __attribute__((ext_vector_type(4))) float f32x4;
typedef __attribute__((ext_vector_type(16))) float f32x16;
typedef __attribute__((ext_vector_type(4))) unsigned int u32x4;

static __device__ __forceinline__ ushort f2bf(float v) {
  __hip_bfloat16 h = __float2bfloat16(v);
  return *reinterpret_cast<ushort*>(&h);
}
static __device__ __forceinline__ float bf2f(ushort u) {
  __hip_bfloat16 h = *reinterpret_cast<__hip_bfloat16*>(&u);
  return __bfloat162float(h);
}
// pack two f32 -> u32 of two bf16 (f0 low, f1 high), RNE via f2bf
static __device__ __forceinline__ unsigned int pk2(float f0, float f1) {
  return (unsigned int)f2bf(f0) | ((unsigned int)f2bf(f1) << 16);
}

static __device__ __forceinline__ void gl_lds16(const void* g, void* l) {
  __builtin_amdgcn_global_load_lds(
      (const __attribute__((address_space(1))) void*)g,
      (__attribute__((address_space(3))) void*)l, 16, 0, 0);
}

// ---------------------------------------------------------------------------
// split f32 -> bf16 hi + lo residual
// ---------------------------------------------------------------------------
__global__ __launch_bounds__(256) void split_bf16_kernel(
    const float* __restrict__ in, ushort* __restrict__ hi,
    ushort* __restrict__ lo, int n4)   // n4 = n/4
{
  const int i = blockIdx.x * 256 + threadIdx.x;
  if (i >= n4) return;
  const float4 v = *(const float4*)(in + (size_t)i * 4);
  ushort4 uh, ul;
  const float vv[4] = {v.x, v.y, v.z, v.w};
#pragma unroll
  for (int j = 0; j < 4; ++j) {
    const ushort hb = f2bf(vv[j]);
    ((ushort*)&uh)[j] = hb;
    ((ushort*)&ul)[j] = f2bf(vv[j] - bf2f(hb));
  }
  *(ushort4*)(hi + (size_t)i * 4) = uh;
  *(ushort4*)(lo + (size_t)i * 4) = ul;
}

// ---------------------------------------------------------------------------
// Split-bf16 MFMA GEMM (unchanged, proven): C = (Ah+Al)(Bh+Bl)^T (+bias)
// ---------------------------------------------------------------------------
template <int MODE>
__global__ __launch_bounds__(256) void mfma_nt_kernel(
    const ushort* __restrict__ Ah, const ushort* __restrict__ Al,
    const ushort* __restrict__ Bh, const ushort* __restrict__ Bl,
    const float* __restrict__ bias, float* __restrict__ Cf,
    ushort* __restrict__ Chi, ushort* __restrict__ Clo, int Nc)
{
  __shared__ ushort lAh[128 * 32];
  __shared__ ushort lAl[128 * 32];
  __shared__ ushort lBh[128 * 32];
  __shared__ ushort lBl[128 * 32];

  const int tid = threadIdx.x;
  const int w = tid >> 6, lane = tid & 63;
  const int c = lane & 15, g = lane >> 4;
  const int wr = (w >> 1) * 64, wc = (w & 1) * 64;
  const int m0 = blockIdx.y * 128, n0 = blockIdx.x * 128;

  const int sr = tid >> 2;
  const int sk = (tid & 3) * 8;

  f32x4 acc[4][4] = {};

  for (int k0 = 0; k0 < GK; k0 += 32) {
    __syncthreads();
    {
      const size_t a1 = (size_t)(m0 + sr) * GK + k0 + sk;
      const size_t b1 = (size_t)(n0 + sr) * GK + k0 + sk;
      const size_t a2 = a1 + (size_t)64 * GK;
      const size_t b2 = b1 + (size_t)64 * GK;
      char* dA  = (char*)lAh + w * 1024;
      char* dAl = (char*)lAl + w * 1024;
      char* dB  = (char*)lBh + w * 1024;
      char* dBl = (char*)lBl + w * 1024;
      gl_lds16(Ah + a1, dA);
      gl_lds16(Al + a1, dAl);
      gl_lds16(Bh + b1, dB);
      gl_lds16(Bl + b1, dBl);
      gl_lds16(Ah + a2, dA + 4096);
      gl_lds16(Al + a2, dAl + 4096);
      gl_lds16(Bh + b2, dB + 4096);
      gl_lds16(Bl + b2, dBl + 4096);
    }
    __syncthreads();

    short8 ah[4], al[4], bh[4], bl[4];
#pragma unroll
    for (int i = 0; i < 4; ++i) {
      const int ar = (wr + i * 16 + c) * 32 + g * 8;
      const int br = (wc + i * 16 + c) * 32 + g * 8;
      ah[i] = *(const short8*)&lAh[ar];
      al[i] = *(const short8*)&lAl[ar];
      bh[i] = *(const short8*)&lBh[br];
      bl[i] = *(const short8*)&lBl[br];
    }
#pragma unroll
    for (int mi = 0; mi < 4; ++mi)
#pragma unroll
      for (int nj = 0; nj < 4; ++nj) {
        acc[mi][nj] = __builtin_amdgcn_mfma_f32_16x16x32_bf16(ah[mi], bl[nj], acc[mi][nj], 0,0,0);
        acc[mi][nj] = __builtin_amdgcn_mfma_f32_16x16x32_bf16(al[mi], bh[nj], acc[mi][nj], 0,0,0);
        acc[mi][nj] = __builtin_amdgcn_mfma_f32_16x16x32_bf16(ah[mi], bh[nj], acc[mi][nj], 0,0,0);
      }
  }

#pragma unroll
  for (int mi = 0; mi < 4; ++mi) {
#pragma unroll
    for (int r = 0; r < 4; ++r) {
      const size_t rb = (size_t)(m0 + wr + mi * 16 + g * 4 + r) * Nc;
#pragma unroll
      for (int nj = 0; nj < 4; ++nj) {
        const int col = n0 + wc + nj * 16 + c;
        const float v = acc[mi][nj][r];
        if (MODE == 0) {
          Cf[rb + col] = v + bias[col];
        } else if (MODE == 1) {
          Chi[rb + col] = f2bf(v);
        } else {
          const ushort hb = f2bf(v);
          Chi[rb + col] = hb;
          Clo[rb + col] = f2bf(v - bf2f(hb));
        }
      }
    }
  }
}

// ---------------------------------------------------------------------------
// Swapped-operand MFMA flash attention, 32x32x16, in-register softmax.
// Block = 128 q-rows x 1 (b,h), 4 waves x 32 q-rows. KV tile = 64 keys.
//
//  S^T = mfma(A=K, B=Qsplit): D[key][q], col q = lane&31, row key =
//        crow(r,hi)=(r&3)+8*(r>>2)+4*hi (+32*kb), hi = lane>>5.
//  Softmax per lane (one q): in-lane 32-value reduce + shfl_xor(32).
//  P -> bf16 A/B-frag slices via pk2 + shfl_xor(32) + select (permlane
//        dataflow): slice ks uses p[8s..8s+7] of block kb=ks>>1, s=ks&1.
//  O^T = mfma(A=V^T, B=P^T): D[d][q], rescale alpha is scalar per lane.
// ---------------------------------------------------------------------------
__global__ __launch_bounds__(256) void attn_mfma2_kernel(
    const ushort* __restrict__ qhi,  // (TQ, C) bf16
    const ushort* __restrict__ qlo,  // (TQ, C) bf16
    const ushort* __restrict__ kbf,  // (B*N, C) bf16
    const ushort* __restrict__ vtb,  // (C, B*N) bf16  (V^T)
    ushort* __restrict__ ohi,        // (TQ, C) bf16 hi
    ushort* __restrict__ olo,        // (TQ, C) bf16 lo
    const int* __restrict__ qlen)    // (B)
{
  // 1D grid decode: lin = b + 8*h + 64*qt  -> all q-tiles of one (b,·)
  // land on the same XCD (blockid % 8 assumed round-robin; perf-only).
  const int lin = blockIdx.x;
  const int b  = lin & 7;
  const int h  = (lin >> 3) & 7;
  const int qt = lin >> 6;

  int off = 0, Lb = 0;
#pragma unroll
  for (int i = 0; i < Bb; ++i) {
    const int Li = qlen[i];
    off += (i < b) ? Li : 0;
    Lb = (i == b) ? Li : Lb;
  }
  if (qt * 128 >= Lb) return;   // uniform; lengths are %128==0

  constexpr int KP = 72;        // padded LDS row stride (bf16): 4-way banks
  __shared__ ushort Ks[64 * KP];   // [key][d]
  __shared__ ushort Vs[64 * KP];   // [d][key]   (from V^T global)

  const int tid = threadIdx.x;
  const int w = tid >> 6;
  const int lane = tid & 63;
  const int l31 = lane & 31;     // this lane's q within the wave tile
  const int hi5 = lane >> 5;

  // Q fragments: B-operand [n=q=l31][k=d=db*16+hi5*8+j], hi + lo
  short8 qfh[4], qfl[4];
  const int qrow = off + qt * 128 + w * 32 + l31;
  {
    const size_t base = (size_t)qrow * Cc + h * Dd + hi5 * 8;
#pragma unroll
    for (int db = 0; db < 4; ++db) {
      qfh[db] = *(const short8*)(qhi + base + db * 16);
      qfl[db] = *(const short8*)(qlo + base + db * 16);
    }
  }

  float m_s = -INFINITY, l_s = 0.f;
  f32x16 accO[2] = {};           // O^T: [ma] rows d=32ma+crow, col q=l31
  const float scale = 0.125f;

  const size_t kbase = (size_t)b * Nn * Cc + h * Dd;
  const size_t vbase = (size_t)h * Dd * (Bb * Nn) + (size_t)b * Nn;

  for (int nt = 0; nt < Nn / 64; ++nt) {
    __syncthreads();   // previous tile's LDS reads complete
#pragma unroll
    for (int it = 0; it < 2; ++it) {
      const int i = tid + it * 256;
      const int row = i >> 3, c8 = (i & 7) * 8;
      *(short8*)&Ks[row * KP + c8] =
          *(const short8*)&kbf[kbase + (size_t)(nt * 64 + row) * Cc + c8];
      *(short8*)&Vs[row * KP + c8] =
          *(const short8*)&vtb[vbase + (size_t)row * (Bb * Nn) + nt * 64 + c8];
    }
    __syncthreads();

    // ---- S^T = K Q^T (split-Q) ----
    f32x16 accT[2] = {};
    __builtin_amdgcn_s_setprio(1);
#pragma unroll
    for (int kb = 0; kb < 2; ++kb) {
#pragma unroll
      for (int db = 0; db < 4; ++db) {
        const short8 kf =
            *(const short8*)&Ks[(kb * 32 + l31) * KP + db * 16 + hi5 * 8];
        accT[kb] = __builtin_amdgcn_mfma_f32_32x32x16_bf16(kf, qfh[db], accT[kb], 0,0,0);
        accT[kb] = __builtin_amdgcn_mfma_f32_32x32x16_bf16(kf, qfl[db], accT[kb], 0,0,0);
      }
    }
    __builtin_amdgcn_s_setprio(0);

    // ---- online softmax, fully in-register (lane owns one q) ----
    float mx = accT[0][0];
#pragma unroll
    for (int r = 1; r < 16; ++r) mx = fmaxf(mx, accT[0][r]);
#pragma unroll
    for (int r = 0; r < 16; ++r) mx = fmaxf(mx, accT[1][r]);
    mx = fmaxf(mx, __shfl_xor(mx, 32));
    const float mn = fmaxf(m_s, mx * scale);
    const float alpha = __expf(m_s - mn);   // first tile: exp(-inf)=0
    m_s = mn;
    float psum = 0.f;
#pragma unroll
    for (int kb = 0; kb < 2; ++kb)
#pragma unroll
      for (int r = 0; r < 16; ++r) {
        const float p = __expf(fmaf(accT[kb][r], scale, -mn));
        accT[kb][r] = p;
        psum += p;
      }
    psum += __shfl_xor(psum, 32);
    l_s = l_s * alpha + psum;
    accO[0] *= alpha;
    accO[1] *= alpha;

    // ---- P -> bf16 fragment slices (keys 16ks..16ks+15) ----
    short8 pa[4];
#pragma unroll
    for (int ks = 0; ks < 4; ++ks) {
      const int kb = ks >> 1, base = (ks & 1) * 8;
      const unsigned int ua = pk2(accT[kb][base + 0], accT[kb][base + 1]);
      const unsigned int uc = pk2(accT[kb][base + 2], accT[kb][base + 3]);
      const unsigned int ub = pk2(accT[kb][base + 4], accT[kb][base + 5]);
      const unsigned int ud = pk2(accT[kb][base + 6], accT[kb][base + 7]);
      const unsigned int sxa = __shfl_xor(ua, 32);
      const unsigned int sxb = __shfl_xor(ub, 32);
      const unsigned int sxc = __shfl_xor(uc, 32);
      const unsigned int sxd = __shfl_xor(ud, 32);
      u32x4 wv;
      wv.x = hi5 ? sxb : ua;   // k' = 8hi+{0,1}
      wv.y = hi5 ? sxd : uc;   // k' = 8hi+{2,3}
      wv.z = hi5 ? ub : sxa;   // k' = 8hi+{4,5}
      wv.w = hi5 ? ud : sxc;   // k' = 8hi+{6,7}
      pa[ks] = __builtin_bit_cast(short8, wv);
    }

    // ---- O^T += V^T P^T ----
    __builtin_amdgcn_s_setprio(1);
#pragma unroll
    for (int ma = 0; ma < 2; ++ma) {
#pragma unroll
      for (int ks = 0; ks < 4; ++ks) {
        const short8 vf =
            *(const short8*)&Vs[(ma * 32 + l31) * KP + ks * 16 + hi5 * 8];
        accO[ma] = __builtin_amdgcn_mfma_f32_32x32x16_bf16(vf, pa[ks], accO[ma], 0,0,0);
      }
    }
    __builtin_amdgcn_s_setprio(0);
  }

  // ---- epilogue: O[q][d] = accO^T / l ----
  const float inv = 1.f / l_s;
  const size_t rb = (size_t)qrow * Cc + h * Dd;
#pragma unroll
  for (int ma = 0; ma < 2; ++ma) {
#pragma unroll
    for (int g2 = 0; g2 < 4; ++g2) {
      const int d0 = ma * 32 + g2 * 8 + hi5 * 4;
      ushort4 uh, ul;
#pragma unroll
      for (int e = 0; e < 4; ++e) {
        const float o = accO[ma][g2 * 4 + e] * inv;
        const ushort hb = f2bf(o);
        ((ushort*)&uh)[e] = hb;
        ((ushort*)&ul)[e] = f2bf(o - bf2f(hb));
      }
      *(ushort4*)&ohi[rb + d0] = uh;
      *(ushort4*)&olo[rb + d0] = ul;
    }
  }
}

// ---------------------------------------------------------------------------
extern "C" void kernel_launch(void* const* d_in, const int* in_sizes, int n_in,
                              void* d_out, int out_size, void* d_ws, size_t ws_size,
                              hipStream_t stream)
{
  const float* x     = (const float*)d_in[0];  // (B,N,C)
  const float* q     = (const float*)d_in[1];  // (TQ,C)
  const float* Wq    = (const float*)d_in[2];  // (C,C)
  const float* Wkv   = (const float*)d_in[3];  // (2C,C): rows [0,C)=Wk, [C,2C)=Wv
  const float* Wproj = (const float*)d_in[4];  // (C,C)
  const float* bproj = (const float*)d_in[5];  // (C)
  const int*   qlen  = (const int*)d_in[6];    // (B)

  const int TQ = in_sizes[1] / Cc;   // 11776 (multiple of 128)
  const int BN = in_sizes[0] / Cc;   // 16384

  const size_t szQ = (size_t)TQ * Cc * 2;
  const size_t szX = (size_t)BN * Cc * 2;
  const size_t szW = (size_t)(4 * Cc) * Cc * 2;

  char* p = (char*)d_ws;
  ushort* qs_hi = (ushort*)p;                       // R1
  ushort* qs_lo = (ushort*)(p + szQ);
  ushort* k_bf  = (ushort*)p;                       // alias (after qh GEMM)
  p += 2 * szQ;
  ushort* xs_hi = (ushort*)p;                       // R2
  ushort* xs_lo = (ushort*)(p + szX);
  ushort* at_hi = (ushort*)p;                       // alias (after v GEMM)
  ushort* at_lo = (ushort*)(p + szQ);
  p += 2 * szX;
  ushort* w_hi  = (ushort*)p;  p += szW;            // [Wq | Wkv | Wproj] hi
  ushort* w_lo  = (ushort*)p;  p += szW;
  ushort* q_hi  = (ushort*)p;  p += szQ;
  ushort* q_lo  = (ushort*)p;  p += szQ;
  ushort* v_t   = (ushort*)p;                       // szX

  ushort* wq_hi = w_hi;
  ushort* wq_lo = w_lo;
  ushort* wk_hi = w_hi + (size_t)Cc * Cc;
  ushort* wk_lo = w_lo + (size_t)Cc * Cc;
  ushort* wv_hi = wk_hi + (size_t)Cc * Cc;
  ushort* wv_lo = wk_lo + (size_t)Cc * Cc;
  ushort* wp_hi = wv_hi + (size_t)Cc * Cc;
  ushort* wp_lo = wv_lo + (size_t)Cc * Cc;

  // --- splits ---
  {
    const int nq = TQ * Cc / 4, nx = BN * Cc / 4;
    const int nwq = Cc * Cc / 4, nwkv = 2 * Cc * Cc / 4;
    split_bf16_kernel<<<(nq + 255)/256, 256, 0, stream>>>(q, qs_hi, qs_lo, nq);
    split_bf16_kernel<<<(nx + 255)/256, 256, 0, stream>>>(x, xs_hi, xs_lo, nx);
    split_bf16_kernel<<<(nwq + 255)/256, 256, 0, stream>>>(Wq, wq_hi, wq_lo, nwq);
    split_bf16_kernel<<<(nwkv + 255)/256, 256, 0, stream>>>(Wkv, wk_hi, wk_lo, nwkv);
    split_bf16_kernel<<<(nwq + 255)/256, 256, 0, stream>>>(Wproj, wp_hi, wp_lo, nwq);
  }

  // 1) q_hi/q_lo = split(q @ Wq^T)       M=TQ, N=C
  mfma_nt_kernel<2><<<dim3(Cc/128, TQ/128), 256, 0, stream>>>(
      qs_hi, qs_lo, wq_hi, wq_lo, nullptr, nullptr, q_hi, q_lo, Cc);
  // 2) k_bf = bf16(x @ Wk^T)             M=BN, N=C   (writes R1 — qs dead now)
  mfma_nt_kernel<1><<<dim3(Cc/128, BN/128), 256, 0, stream>>>(
      xs_hi, xs_lo, wk_hi, wk_lo, nullptr, nullptr, k_bf, nullptr, Cc);
  // 3) v_t = bf16(Wv @ x^T)              M=C, N=BN
  mfma_nt_kernel<1><<<dim3(BN/128, Cc/128), 256, 0, stream>>>(
      wv_hi, wv_lo, xs_hi, xs_lo, nullptr, nullptr, v_t, nullptr, BN);
  // 4) attention (swapped 32x32, 128-row blocks; writes hi/lo into R2)
  attn_mfma2_kernel<<<dim3(64 * (1920 / 128)), 256, 0, stream>>>(
      q_hi, q_lo, k_bf, v_t, at_hi, at_lo, qlen);
  // 5) out = attno @ Wproj^T + bproj     M=TQ, N=C
  mfma_nt_kernel<0><<<dim3(Cc/128, TQ/128), 256, 0, stream>>>(
      at_hi, at_lo, wp_hi, wp_lo, bproj, (float*)d_out, nullptr, nullptr, Cc);
}

// Round 6
// 294.534 us; speedup vs baseline: 5.1728x; 1.0017x over previous
//
#include <hip/hip_runtime.h>
#include <hip/hip_bf16.h>
#include <math.h>

// Problem constants (fixed by the reference):
constexpr int Cc = 512;   // channels
constexpr int Hh = 8;     // heads
constexpr int Dd = 64;    // head dim
constexpr int Nn = 2048;  // kv length
constexpr int Bb = 8;     // batch
constexpr int GK = 512;   // K dim of every GEMM here

typedef __attribute__((ext_vector_type(8))) short short8;
typedef __attribute__((ext_vector_type(4))) float f32x4;
typedef __attribute__((ext_vector_type(16))) float f32x16;
typedef __attribute__((ext_vector_type(4))) unsigned int u32x4;

static __device__ __forceinline__ ushort f2bf(float v) {
  __hip_bfloat16 h = __float2bfloat16(v);
  return *reinterpret_cast<ushort*>(&h);
}
static __device__ __forceinline__ float bf2f(ushort u) {
  __hip_bfloat16 h = *reinterpret_cast<__hip_bfloat16*>(&u);
  return __bfloat162float(h);
}
// pack two f32 -> u32 of two bf16 (f0 low, f1 high), RNE via f2bf
static __device__ __forceinline__ unsigned int pk2(float f0, float f1) {
  return (unsigned int)f2bf(f0) | ((unsigned int)f2bf(f1) << 16);
}

static __device__ __forceinline__ void gl_lds16(const void* g, void* l) {
  __builtin_amdgcn_global_load_lds(
      (const __attribute__((address_space(1))) void*)g,
      (__attribute__((address_space(3))) void*)l, 16, 0, 0);
}

// ---------------------------------------------------------------------------
// split f32 -> bf16 hi + lo residual
// ---------------------------------------------------------------------------
__global__ __launch_bounds__(256) void split_bf16_kernel(
    const float* __restrict__ in, ushort* __restrict__ hi,
    ushort* __restrict__ lo, int n4)   // n4 = n/4
{
  const int i = blockIdx.x * 256 + threadIdx.x;
  if (i >= n4) return;
  const float4 v = *(const float4*)(in + (size_t)i * 4);
  ushort4 uh, ul;
  const float vv[4] = {v.x, v.y, v.z, v.w};
#pragma unroll
  for (int j = 0; j < 4; ++j) {
    const ushort hb = f2bf(vv[j]);
    ((ushort*)&uh)[j] = hb;
    ((ushort*)&ul)[j] = f2bf(vv[j] - bf2f(hb));
  }
  *(ushort4*)(hi + (size_t)i * 4) = uh;
  *(ushort4*)(lo + (size_t)i * 4) = ul;
}

// ---------------------------------------------------------------------------
// Split-bf16 MFMA GEMM (unchanged, proven): C = (Ah+Al)(Bh+Bl)^T (+bias)
// ---------------------------------------------------------------------------
template <int MODE>
__global__ __launch_bounds__(256) void mfma_nt_kernel(
    const ushort* __restrict__ Ah, const ushort* __restrict__ Al,
    const ushort* __restrict__ Bh, const ushort* __restrict__ Bl,
    const float* __restrict__ bias, float* __restrict__ Cf,
    ushort* __restrict__ Chi, ushort* __restrict__ Clo, int Nc)
{
  __shared__ ushort lAh[128 * 32];
  __shared__ ushort lAl[128 * 32];
  __shared__ ushort lBh[128 * 32];
  __shared__ ushort lBl[128 * 32];

  const int tid = threadIdx.x;
  const int w = tid >> 6, lane = tid & 63;
  const int c = lane & 15, g = lane >> 4;
  const int wr = (w >> 1) * 64, wc = (w & 1) * 64;
  const int m0 = blockIdx.y * 128, n0 = blockIdx.x * 128;

  const int sr = tid >> 2;
  const int sk = (tid & 3) * 8;

  f32x4 acc[4][4] = {};

  for (int k0 = 0; k0 < GK; k0 += 32) {
    __syncthreads();
    {
      const size_t a1 = (size_t)(m0 + sr) * GK + k0 + sk;
      const size_t b1 = (size_t)(n0 + sr) * GK + k0 + sk;
      const size_t a2 = a1 + (size_t)64 * GK;
      const size_t b2 = b1 + (size_t)64 * GK;
      char* dA  = (char*)lAh + w * 1024;
      char* dAl = (char*)lAl + w * 1024;
      char* dB  = (char*)lBh + w * 1024;
      char* dBl = (char*)lBl + w * 1024;
      gl_lds16(Ah + a1, dA);
      gl_lds16(Al + a1, dAl);
      gl_lds16(Bh + b1, dB);
      gl_lds16(Bl + b1, dBl);
      gl_lds16(Ah + a2, dA + 4096);
      gl_lds16(Al + a2, dAl + 4096);
      gl_lds16(Bh + b2, dB + 4096);
      gl_lds16(Bl + b2, dBl + 4096);
    }
    __syncthreads();

    short8 ah[4], al[4], bh[4], bl[4];
#pragma unroll
    for (int i = 0; i < 4; ++i) {
      const int ar = (wr + i * 16 + c) * 32 + g * 8;
      const int br = (wc + i * 16 + c) * 32 + g * 8;
      ah[i] = *(const short8*)&lAh[ar];
      al[i] = *(const short8*)&lAl[ar];
      bh[i] = *(const short8*)&lBh[br];
      bl[i] = *(const short8*)&lBl[br];
    }
#pragma unroll
    for (int mi = 0; mi < 4; ++mi)
#pragma unroll
      for (int nj = 0; nj < 4; ++nj) {
        acc[mi][nj] = __builtin_amdgcn_mfma_f32_16x16x32_bf16(ah[mi], bl[nj], acc[mi][nj], 0,0,0);
        acc[mi][nj] = __builtin_amdgcn_mfma_f32_16x16x32_bf16(al[mi], bh[nj], acc[mi][nj], 0,0,0);
        acc[mi][nj] = __builtin_amdgcn_mfma_f32_16x16x32_bf16(ah[mi], bh[nj], acc[mi][nj], 0,0,0);
      }
  }

#pragma unroll
  for (int mi = 0; mi < 4; ++mi) {
#pragma unroll
    for (int r = 0; r < 4; ++r) {
      const size_t rb = (size_t)(m0 + wr + mi * 16 + g * 4 + r) * Nc;
#pragma unroll
      for (int nj = 0; nj < 4; ++nj) {
        const int col = n0 + wc + nj * 16 + c;
        const float v = acc[mi][nj][r];
        if (MODE == 0) {
          Cf[rb + col] = v + bias[col];
        } else if (MODE == 1) {
          Chi[rb + col] = f2bf(v);
        } else {
          const ushort hb = f2bf(v);
          Chi[rb + col] = hb;
          Clo[rb + col] = f2bf(v - bf2f(hb));
        }
      }
    }
  }
}

// ---------------------------------------------------------------------------
// Swapped-operand MFMA flash attention, 32x32x16, in-register softmax,
// double-buffered LDS with async-stage split (issue-early / write-late).
// Block = 128 q-rows x 1 (b,h), 4 waves x 32 q-rows. KV tile = 64 keys.
// ---------------------------------------------------------------------------
__global__ __launch_bounds__(256) void attn_mfma2_kernel(
    const ushort* __restrict__ qhi,  // (TQ, C) bf16
    const ushort* __restrict__ qlo,  // (TQ, C) bf16
    const ushort* __restrict__ kbf,  // (B*N, C) bf16
    const ushort* __restrict__ vtb,  // (C, B*N) bf16  (V^T)
    ushort* __restrict__ ohi,        // (TQ, C) bf16 hi
    ushort* __restrict__ olo,        // (TQ, C) bf16 lo
    const int* __restrict__ qlen)    // (B)
{
  const int lin = blockIdx.x;
  const int b  = lin & 7;
  const int h  = (lin >> 3) & 7;
  const int qt = lin >> 6;

  int off = 0, Lb = 0;
#pragma unroll
  for (int i = 0; i < Bb; ++i) {
    const int Li = qlen[i];
    off += (i < b) ? Li : 0;
    Lb = (i == b) ? Li : Lb;
  }
  if (qt * 128 >= Lb) return;   // uniform; lengths are %128==0

  constexpr int KP = 72;        // padded LDS row stride (bf16): conflict-free
  constexpr int NT = Nn / 64;
  __shared__ ushort Ks[2][64 * KP];   // [buf][key][d]
  __shared__ ushort Vs[2][64 * KP];   // [buf][d][key]   (from V^T global)

  const int tid = threadIdx.x;
  const int w = tid >> 6;
  const int lane = tid & 63;
  const int l31 = lane & 31;     // this lane's q within the wave tile
  const int hi5 = lane >> 5;

  const size_t kbase = (size_t)b * Nn * Cc + h * Dd;
  const size_t vbase = (size_t)h * Dd * (Bb * Nn) + (size_t)b * Nn;

  // staging row/col for this thread (2 chunks of 256 threads)
  const int srow0 = tid >> 3,        sc0 = (tid & 7) * 8;
  const int srow1 = (tid + 256) >> 3, sc1 = ((tid + 256) & 7) * 8;

  auto loadkv = [&](int nt_, short8* kr, short8* vr) {
    kr[0] = *(const short8*)&kbf[kbase + (size_t)(nt_ * 64 + srow0) * Cc + sc0];
    vr[0] = *(const short8*)&vtb[vbase + (size_t)srow0 * (Bb * Nn) + nt_ * 64 + sc0];
    kr[1] = *(const short8*)&kbf[kbase + (size_t)(nt_ * 64 + srow1) * Cc + sc1];
    vr[1] = *(const short8*)&vtb[vbase + (size_t)srow1 * (Bb * Nn) + nt_ * 64 + sc1];
  };
  auto writekv = [&](int buf, const short8* kr, const short8* vr) {
    *(short8*)&Ks[buf][srow0 * KP + sc0] = kr[0];
    *(short8*)&Vs[buf][srow0 * KP + sc0] = vr[0];
    *(short8*)&Ks[buf][srow1 * KP + sc1] = kr[1];
    *(short8*)&Vs[buf][srow1 * KP + sc1] = vr[1];
  };

  // Q fragments: B-operand [n=q=l31][k=d=db*16+hi5*8+j], hi + lo
  short8 qfh[4], qfl[4];
  const int qrow = off + qt * 128 + w * 32 + l31;
  {
    const size_t base = (size_t)qrow * Cc + h * Dd + hi5 * 8;
#pragma unroll
    for (int db = 0; db < 4; ++db) {
      qfh[db] = *(const short8*)(qhi + base + db * 16);
      qfl[db] = *(const short8*)(qlo + base + db * 16);
    }
  }

  float m_s = -INFINITY, l_s = 0.f;     // m_s in log2 domain
  f32x16 accO[2] = {};                  // O^T: [ma] rows d=32ma+crow, col q
  const float C2 = 0.125f * 1.44269504089f;   // scale * log2(e)

  short8 krg[2], vrg[2];
  loadkv(0, krg, vrg);
  writekv(0, krg, vrg);
  __syncthreads();

  for (int nt = 0; nt < NT; ++nt) {
    const int cur = nt & 1;
    const bool more = (nt + 1 < NT);
    if (more) loadkv(nt + 1, krg, vrg);   // issue early; lands before writekv

    const ushort* Kc = &Ks[cur][0];
    const ushort* Vc = &Vs[cur][0];

    // ---- S^T = K Q^T (split-Q) ----
    f32x16 accT[2] = {};
    __builtin_amdgcn_s_setprio(1);
#pragma unroll
    for (int kb = 0; kb < 2; ++kb) {
#pragma unroll
      for (int db = 0; db < 4; ++db) {
        const short8 kf =
            *(const short8*)&Kc[(kb * 32 + l31) * KP + db * 16 + hi5 * 8];
        accT[kb] = __builtin_amdgcn_mfma_f32_32x32x16_bf16(kf, qfh[db], accT[kb], 0,0,0);
        accT[kb] = __builtin_amdgcn_mfma_f32_32x32x16_bf16(kf, qfl[db], accT[kb], 0,0,0);
      }
    }
    __builtin_amdgcn_s_setprio(0);

    // ---- online softmax, in-register, exp2 domain (tree reductions) ----
    float t8[8];
#pragma unroll
    for (int r = 0; r < 8; ++r)
      t8[r] = fmaxf(fmaxf(accT[0][r], accT[0][r + 8]),
                    fmaxf(accT[1][r], accT[1][r + 8]));
    float mx = fmaxf(fmaxf(fmaxf(t8[0], t8[1]), fmaxf(t8[2], t8[3])),
                     fmaxf(fmaxf(t8[4], t8[5]), fmaxf(t8[6], t8[7])));
    mx = fmaxf(mx, __shfl_xor(mx, 32));
    const float mn2 = fmaxf(m_s, mx * C2);
    const float alpha = __builtin_amdgcn_exp2f(m_s - mn2);  // first: exp2(-inf)=0
    m_s = mn2;
    float ps[4] = {0.f, 0.f, 0.f, 0.f};
#pragma unroll
    for (int kb = 0; kb < 2; ++kb)
#pragma unroll
      for (int r = 0; r < 16; ++r) {
        const float p = __builtin_amdgcn_exp2f(fmaf(accT[kb][r], C2, -mn2));
        accT[kb][r] = p;
        ps[r & 3] += p;
      }
    float psum = (ps[0] + ps[1]) + (ps[2] + ps[3]);
    psum += __shfl_xor(psum, 32);
    l_s = l_s * alpha + psum;
    accO[0] *= alpha;
    accO[1] *= alpha;

    // ---- P -> bf16 fragment slices (keys 16ks..16ks+15) ----
    short8 pa[4];
#pragma unroll
    for (int ks = 0; ks < 4; ++ks) {
      const int kb = ks >> 1, base = (ks & 1) * 8;
      const unsigned int ua = pk2(accT[kb][base + 0], accT[kb][base + 1]);
      const unsigned int uc = pk2(accT[kb][base + 2], accT[kb][base + 3]);
      const unsigned int ub = pk2(accT[kb][base + 4], accT[kb][base + 5]);
      const unsigned int ud = pk2(accT[kb][base + 6], accT[kb][base + 7]);
      const unsigned int sxa = __shfl_xor(ua, 32);
      const unsigned int sxb = __shfl_xor(ub, 32);
      const unsigned int sxc = __shfl_xor(uc, 32);
      const unsigned int sxd = __shfl_xor(ud, 32);
      u32x4 wv;
      wv.x = hi5 ? sxb : ua;   // k' = 8hi+{0,1}
      wv.y = hi5 ? sxd : uc;   // k' = 8hi+{2,3}
      wv.z = hi5 ? ub : sxa;   // k' = 8hi+{4,5}
      wv.w = hi5 ? ud : sxc;   // k' = 8hi+{6,7}
      pa[ks] = __builtin_bit_cast(short8, wv);
    }

    // ---- O^T += V^T P^T ----
    __builtin_amdgcn_s_setprio(1);
#pragma unroll
    for (int ma = 0; ma < 2; ++ma) {
#pragma unroll
      for (int ks = 0; ks < 4; ++ks) {
        const short8 vf =
            *(const short8*)&Vc[(ma * 32 + l31) * KP + ks * 16 + hi5 * 8];
        accO[ma] = __builtin_amdgcn_mfma_f32_32x32x16_bf16(vf, pa[ks], accO[ma], 0,0,0);
      }
    }
    __builtin_amdgcn_s_setprio(0);

    if (more) {
      writekv(cur ^ 1, krg, vrg);   // safe: buf last read in iter nt-1
      __syncthreads();              // writes visible for iter nt+1
    }
  }

  // ---- epilogue: O[q][d] = accO^T / l ----
  const float inv = 1.f / l_s;
  const size_t rb = (size_t)qrow * Cc + h * Dd;
#pragma unroll
  for (int ma = 0; ma < 2; ++ma) {
#pragma unroll
    for (int g2 = 0; g2 < 4; ++g2) {
      const int d0 = ma * 32 + g2 * 8 + hi5 * 4;
      ushort4 uh, ul;
#pragma unroll
      for (int e = 0; e < 4; ++e) {
        const float o = accO[ma][g2 * 4 + e] * inv;
        const ushort hb = f2bf(o);
        ((ushort*)&uh)[e] = hb;
        ((ushort*)&ul)[e] = f2bf(o - bf2f(hb));
      }
      *(ushort4*)&ohi[rb + d0] = uh;
      *(ushort4*)&olo[rb + d0] = ul;
    }
  }
}

// ---------------------------------------------------------------------------
extern "C" void kernel_launch(void* const* d_in, const int* in_sizes, int n_in,
                              void* d_out, int out_size, void* d_ws, size_t ws_size,
                              hipStream_t stream)
{
  const float* x     = (const float*)d_in[0];  // (B,N,C)
  const float* q     = (const float*)d_in[1];  // (TQ,C)
  const float* Wq    = (const float*)d_in[2];  // (C,C)
  const float* Wkv   = (const float*)d_in[3];  // (2C,C): rows [0,C)=Wk, [C,2C)=Wv
  const float* Wproj = (const float*)d_in[4];  // (C,C)
  const float* bproj = (const float*)d_in[5];  // (C)
  const int*   qlen  = (const int*)d_in[6];    // (B)

  const int TQ = in_sizes[1] / Cc;   // 11776 (multiple of 128)
  const int BN = in_sizes[0] / Cc;   // 16384

  const size_t szQ = (size_t)TQ * Cc * 2;
  const size_t szX = (size_t)BN * Cc * 2;
  const size_t szW = (size_t)(4 * Cc) * Cc * 2;

  char* p = (char*)d_ws;
  ushort* qs_hi = (ushort*)p;                       // R1
  ushort* qs_lo = (ushort*)(p + szQ);
  ushort* k_bf  = (ushort*)p;                       // alias (after qh GEMM)
  p += 2 * szQ;
  ushort* xs_hi = (ushort*)p;                       // R2
  ushort* xs_lo = (ushort*)(p + szX);
  ushort* at_hi = (ushort*)p;                       // alias (after v GEMM)
  ushort* at_lo = (ushort*)(p + szQ);
  p += 2 * szX;
  ushort* w_hi  = (ushort*)p;  p += szW;            // [Wq | Wkv | Wproj] hi
  ushort* w_lo  = (ushort*)p;  p += szW;
  ushort* q_hi  = (ushort*)p;  p += szQ;
  ushort* q_lo  = (ushort*)p;  p += szQ;
  ushort* v_t   = (ushort*)p;                       // szX

  ushort* wq_hi = w_hi;
  ushort* wq_lo = w_lo;
  ushort* wk_hi = w_hi + (size_t)Cc * Cc;
  ushort* wk_lo = w_lo + (size_t)Cc * Cc;
  ushort* wv_hi = wk_hi + (size_t)Cc * Cc;
  ushort* wv_lo = wk_lo + (size_t)Cc * Cc;
  ushort* wp_hi = wv_hi + (size_t)Cc * Cc;
  ushort* wp_lo = wv_lo + (size_t)Cc * Cc;

  // --- splits ---
  {
    const int nq = TQ * Cc / 4, nx = BN * Cc / 4;
    const int nwq = Cc * Cc / 4, nwkv = 2 * Cc * Cc / 4;
    split_bf16_kernel<<<(nq + 255)/256, 256, 0, stream>>>(q, qs_hi, qs_lo, nq);
    split_bf16_kernel<<<(nx + 255)/256, 256, 0, stream>>>(x, xs_hi, xs_lo, nx);
    split_bf16_kernel<<<(nwq + 255)/256, 256, 0, stream>>>(Wq, wq_hi, wq_lo, nwq);
    split_bf16_kernel<<<(nwkv + 255)/256, 256, 0, stream>>>(Wkv, wk_hi, wk_lo, nwkv);
    split_bf16_kernel<<<(nwq + 255)/256, 256, 0, stream>>>(Wproj, wp_hi, wp_lo, nwq);
  }

  // 1) q_hi/q_lo = split(q @ Wq^T)       M=TQ, N=C
  mfma_nt_kernel<2><<<dim3(Cc/128, TQ/128), 256, 0, stream>>>(
      qs_hi, qs_lo, wq_hi, wq_lo, nullptr, nullptr, q_hi, q_lo, Cc);
  // 2) k_bf = bf16(x @ Wk^T)             M=BN, N=C   (writes R1 — qs dead now)
  mfma_nt_kernel<1><<<dim3(Cc/128, BN/128), 256, 0, stream>>>(
      xs_hi, xs_lo, wk_hi, wk_lo, nullptr, nullptr, k_bf, nullptr, Cc);
  // 3) v_t = bf16(Wv @ x^T)              M=C, N=BN
  mfma_nt_kernel<1><<<dim3(BN/128, Cc/128), 256, 0, stream>>>(
      wv_hi, wv_lo, xs_hi, xs_lo, nullptr, nullptr, v_t, nullptr, BN);
  // 4) attention (swapped 32x32, 128-row blocks, dbuf; writes hi/lo into R2)
  attn_mfma2_kernel<<<dim3(64 * (1920 / 128)), 256, 0, stream>>>(
      q_hi, q_lo, k_bf, v_t, at_hi, at_lo, qlen);
  // 5) out = attno @ Wproj^T + bproj     M=TQ, N=C
  mfma_nt_kernel<0><<<dim3(Cc/128, TQ/128), 256, 0, stream>>>(
      at_hi, at_lo, wp_hi, wp_lo, bproj, (float*)d_out, nullptr, nullptr, Cc);
}